// Round 1
// baseline (217.974 us; speedup 1.0000x reference)
//
#include <hip/hip_runtime.h>
#include <math.h>

#define EMBED 512
#define NQ 8
#define SEQ 2048
#define NB 8

// ---------------------------------------------------------------------------
// k0: transpose rotation (512 x 8) -> RT (8 x 512) so k1 can vector-load it.
// ---------------------------------------------------------------------------
__global__ __launch_bounds__(256) void qa_k0_transpose(
    const float* __restrict__ R, float* __restrict__ RT) {
    int t = blockIdx.x * 256 + threadIdx.x;
    if (t < EMBED * NQ) {
        int e = t >> 3;
        int q = t & 7;
        RT[q * EMBED + e] = R[e * NQ + q];
    }
}

// ---------------------------------------------------------------------------
// k1: rotT[b][q][i] = sum_e x[b][i][e] * R[e][q]
// Thread layout: q = tid&7, row-slot = tid>>3. Each thread does a full K=512
// dot via float4 x float4 (no cross-lane reduction needed). x loads are
// 8-way duplicated across q-lanes but L1-resident after first touch;
// HBM traffic = 32 MiB (the x read floor).
// ---------------------------------------------------------------------------
__global__ __launch_bounds__(256) void qa_k1_rot(
    const float* __restrict__ x, const float* __restrict__ RT,
    float* __restrict__ rotT) {
    const int q = threadIdx.x & 7;
    const int rslot = threadIdx.x >> 3;           // 0..31
    const int b = blockIdx.x >> 6;                // 64 blocks per batch
    const int i = ((blockIdx.x & 63) << 5) + rslot;

    const float4* __restrict__ xr =
        (const float4*)(x + ((size_t)b * SEQ + i) * EMBED);
    const float4* __restrict__ rr = (const float4*)(RT + q * EMBED);

    float acc = 0.f;
#pragma unroll 8
    for (int m = 0; m < EMBED / 4; ++m) {
        float4 a = xr[m];
        float4 r = rr[m];
        acc = fmaf(a.x, r.x, acc);
        acc = fmaf(a.y, r.y, acc);
        acc = fmaf(a.z, r.z, acc);
        acc = fmaf(a.w, r.w, acc);
    }
    rotT[(size_t)b * (NQ * SEQ) + (size_t)q * SEQ + i] = acc;
}

// ---------------------------------------------------------------------------
// k2: scores[b][i][j] = sigmoid(rot_i . rot_j) / rowsum
// Block = 256 threads = 4 waves; each wave owns TI=8 rows -> 32 rows/block,
// 64 blocks/batch, grid = 512. rotT[b] staged in LDS as [q][j] (64 KiB):
// lane-stride-1 b32 reads = 2 lanes/bank = conflict-free. TI=8 amortizes
// each rot_j LDS read across 8 rows (LDS traffic / 8). Two passes (rowsum,
// then normalize+store) avoid a 128-VGPR probs array; sigmoid recompute is
// bit-identical between passes.
// ---------------------------------------------------------------------------
#define TI 8
#define K2_THREADS 256
#define ROWS_PER_BLOCK 32   // 4 waves * TI

__global__ __launch_bounds__(K2_THREADS) void qa_k2_scores(
    const float* __restrict__ rotT, float* __restrict__ out) {
    __shared__ float lds[NQ * SEQ];               // 64 KiB, [q][j]
    const int b = blockIdx.x >> 6;                // 64 blocks per batch
    const int i0blk = (blockIdx.x & 63) * ROWS_PER_BLOCK;
    const float* __restrict__ rt = rotT + (size_t)b * (NQ * SEQ);

    // Stage rotT[b] (16384 floats) cooperatively, coalesced float4.
    {
        const float4* __restrict__ src = (const float4*)rt;
        float4* dst = (float4*)lds;
#pragma unroll
        for (int m = 0; m < (NQ * SEQ / 4) / K2_THREADS; ++m)
            dst[threadIdx.x + m * K2_THREADS] = src[threadIdx.x + m * K2_THREADS];
    }
    __syncthreads();

    const int wave = threadIdx.x >> 6;
    const int lane = threadIdx.x & 63;
    const int i0 = i0blk + wave * TI;

    // rot_i fragments for this wave's 8 rows (broadcast LDS reads — free).
    float ri[TI][NQ];
#pragma unroll
    for (int r = 0; r < TI; ++r)
#pragma unroll
        for (int q = 0; q < NQ; ++q)
            ri[r][q] = lds[q * SEQ + i0 + r];

    // ---- Pass A: row sums ----
    float rsum[TI];
#pragma unroll
    for (int r = 0; r < TI; ++r) rsum[r] = 0.f;

    for (int j0 = 0; j0 < SEQ; j0 += 64) {
        const int j = j0 + lane;
        float rj[NQ];
#pragma unroll
        for (int q = 0; q < NQ; ++q) rj[q] = lds[q * SEQ + j];
#pragma unroll
        for (int r = 0; r < TI; ++r) {
            float s = 0.f;
#pragma unroll
            for (int q = 0; q < NQ; ++q) s = fmaf(ri[r][q], rj[q], s);
            rsum[r] += 1.f / (1.f + __expf(-s));
        }
    }

    // Butterfly reduce each rowsum over 64 lanes; keep the inverse.
#pragma unroll
    for (int r = 0; r < TI; ++r) {
#pragma unroll
        for (int off = 32; off > 0; off >>= 1)
            rsum[r] += __shfl_xor(rsum[r], off);
        rsum[r] = 1.f / rsum[r];
    }

    // ---- Pass B: recompute (bit-identical), normalize, store ----
    float* __restrict__ orow = out + ((size_t)b * SEQ + i0) * SEQ;
    for (int j0 = 0; j0 < SEQ; j0 += 64) {
        const int j = j0 + lane;
        float rj[NQ];
#pragma unroll
        for (int q = 0; q < NQ; ++q) rj[q] = lds[q * SEQ + j];
#pragma unroll
        for (int r = 0; r < TI; ++r) {
            float s = 0.f;
#pragma unroll
            for (int q = 0; q < NQ; ++q) s = fmaf(ri[r][q], rj[q], s);
            float p = 1.f / (1.f + __expf(-s));
            __builtin_nontemporal_store(p * rsum[r], orow + (size_t)r * SEQ + j);
        }
    }
}

// ---------------------------------------------------------------------------
extern "C" void kernel_launch(void* const* d_in, const int* in_sizes, int n_in,
                              void* d_out, int out_size, void* d_ws, size_t ws_size,
                              hipStream_t stream) {
    const float* x        = (const float*)d_in[0];  // (8, 2048, 512) fp32
    const float* rotation = (const float*)d_in[1];  // (512, 8) fp32
    float* out = (float*)d_out;                     // (8, 2048, 2048) fp32

    float* RT   = (float*)d_ws;                     // 8 x 512   = 16 KiB
    float* rotT = (float*)d_ws + EMBED * NQ;        // 8 x 8 x 2048 = 512 KiB

    qa_k0_transpose<<<(EMBED * NQ + 255) / 256, 256, 0, stream>>>(rotation, RT);
    qa_k1_rot<<<NB * 64, 256, 0, stream>>>(x, RT, rotT);
    qa_k2_scores<<<NB * 64, K2_THREADS, 0, stream>>>(rotT, out);
}

// Round 3
// 174.724 us; speedup vs baseline: 1.2475x; 1.2475x over previous
//
#include <hip/hip_runtime.h>
#include <math.h>

#define EMBED 512
#define NQ 8
#define SEQ 2048
#define NB 8
#define LOG2E 1.4426950408889634f

typedef float vfloat4 __attribute__((ext_vector_type(4)));  // clang vector: valid for nontemporal builtins

// ---------------------------------------------------------------------------
// k1: rotT[b][q][i] = sum_e x[b][i][e] * R[e][q]
// Rotation transpose fused in: stage R (512x8) into LDS as [q][e] with row
// stride 516 (516*4 B = 16B-aligned rows; distinct bank quads per q-row).
// Thread (q = tid&7, rslot = tid>>3) computes one full K=512 dot with
// vfloat4 x vfloat4; x loads 8-way lane-duplicated (L1 absorbs).
// ---------------------------------------------------------------------------
#define RPAD 516

__global__ __launch_bounds__(256) void qa_rot(
    const float* __restrict__ x, const float* __restrict__ R,
    float* __restrict__ rotT) {
    __shared__ float rt[NQ * RPAD];
#pragma unroll
    for (int m = 0; m < (EMBED * NQ) / 256; ++m) {
        int f = threadIdx.x + m * 256;
        rt[(f & 7) * RPAD + (f >> 3)] = R[f];
    }
    __syncthreads();

    const int q = threadIdx.x & 7;
    const int rslot = threadIdx.x >> 3;           // 0..31
    const int b = blockIdx.x >> 6;                // 64 blocks per batch
    const int i = ((blockIdx.x & 63) << 5) + rslot;

    const vfloat4* __restrict__ xr =
        (const vfloat4*)(x + ((size_t)b * SEQ + i) * EMBED);
    const vfloat4* __restrict__ rr = (const vfloat4*)(rt + q * RPAD);

    float acc = 0.f;
#pragma unroll 8
    for (int m = 0; m < EMBED / 4; ++m) {
        vfloat4 a = xr[m];
        vfloat4 r = rr[m];
        acc = fmaf(a.x, r.x, acc);
        acc = fmaf(a.y, r.y, acc);
        acc = fmaf(a.z, r.z, acc);
        acc = fmaf(a.w, r.w, acc);
    }
    rotT[(size_t)b * (NQ * SEQ) + (size_t)q * SEQ + i] = acc;
}

// ---------------------------------------------------------------------------
// k2: scores[b][i][j] = sigmoid(rot_i . rot_j) / rowsum — SINGLE PASS.
// Block = 256 thr = 4 waves; wave owns TI=2 rows -> 8 rows/block,
// 256 blocks/batch, grid 2048. rotT[b] in LDS [q][j] (64 KiB).
// Each lane owns 4 consecutive j per tile: ds_read_b128 + dwordx4 stores.
// probs for the whole row pair live in 64 VGPRs -> sigmoid computed ONCE.
// Sigmoid = v_rcp(1 + v_exp2(-s*log2e)) — no IEEE div sequence.
// ---------------------------------------------------------------------------
#define K2_THREADS 256
#define TI 2
#define ROWS_PER_BLOCK 8    // 4 waves * TI

__global__ __launch_bounds__(K2_THREADS) void qa_scores(
    const float* __restrict__ rotT, float* __restrict__ out) {
    __shared__ float lds[NQ * SEQ];               // 64 KiB, [q][j]
    const int b = blockIdx.x >> 8;                // 256 blocks per batch
    const int i0blk = (blockIdx.x & 255) * ROWS_PER_BLOCK;
    const float* __restrict__ rt = rotT + (size_t)b * (NQ * SEQ);

    // Stage rotT[b] (16384 floats) cooperatively, coalesced 16B.
    {
        const vfloat4* __restrict__ src = (const vfloat4*)rt;
        vfloat4* dst = (vfloat4*)lds;
#pragma unroll
        for (int m = 0; m < (NQ * SEQ / 4) / K2_THREADS; ++m)
            dst[threadIdx.x + m * K2_THREADS] = src[threadIdx.x + m * K2_THREADS];
    }
    __syncthreads();

    const int wave = threadIdx.x >> 6;
    const int lane = threadIdx.x & 63;
    const int i0 = i0blk + wave * TI;

    // rot_i for this wave's 2 rows (broadcast LDS reads).
    float ri[TI][NQ];
#pragma unroll
    for (int r = 0; r < TI; ++r)
#pragma unroll
        for (int q = 0; q < NQ; ++q)
            ri[r][q] = lds[q * SEQ + i0 + r];

    // 8 tiles of 256 j each; lane owns j = t*256 + 4*lane .. +3.
    vfloat4 pv[8][TI];                             // 64 VGPRs of probs
    float rsum[TI] = {0.f, 0.f};

#pragma unroll
    for (int t = 0; t < 8; ++t) {
        vfloat4 rj[NQ];
#pragma unroll
        for (int q = 0; q < NQ; ++q)
            rj[q] = *((const vfloat4*)(lds + q * SEQ + t * 256) + lane);
#pragma unroll
        for (int r = 0; r < TI; ++r) {
            vfloat4 s = {0.f, 0.f, 0.f, 0.f};
#pragma unroll
            for (int q = 0; q < NQ; ++q) {
                s.x = fmaf(ri[r][q], rj[q].x, s.x);
                s.y = fmaf(ri[r][q], rj[q].y, s.y);
                s.z = fmaf(ri[r][q], rj[q].z, s.z);
                s.w = fmaf(ri[r][q], rj[q].w, s.w);
            }
            vfloat4 p;
            p.x = __builtin_amdgcn_rcpf(1.f + __builtin_amdgcn_exp2f(-s.x * LOG2E));
            p.y = __builtin_amdgcn_rcpf(1.f + __builtin_amdgcn_exp2f(-s.y * LOG2E));
            p.z = __builtin_amdgcn_rcpf(1.f + __builtin_amdgcn_exp2f(-s.z * LOG2E));
            p.w = __builtin_amdgcn_rcpf(1.f + __builtin_amdgcn_exp2f(-s.w * LOG2E));
            pv[t][r] = p;
            rsum[r] += (p.x + p.y) + (p.z + p.w);
        }
    }

    // Butterfly reduce rowsums over 64 lanes; keep inverse.
#pragma unroll
    for (int r = 0; r < TI; ++r) {
#pragma unroll
        for (int off = 32; off > 0; off >>= 1)
            rsum[r] += __shfl_xor(rsum[r], off);
        rsum[r] = __builtin_amdgcn_rcpf(rsum[r]);
    }

    // Normalize from registers and store (dwordx4, nontemporal).
#pragma unroll
    for (int r = 0; r < TI; ++r) {
        float* __restrict__ orow = out + ((size_t)b * SEQ + i0 + r) * SEQ;
#pragma unroll
        for (int t = 0; t < 8; ++t) {
            vfloat4 v = pv[t][r] * rsum[r];
            __builtin_nontemporal_store(v, (vfloat4*)(orow + t * 256) + lane);
        }
    }
}

// ---------------------------------------------------------------------------
extern "C" void kernel_launch(void* const* d_in, const int* in_sizes, int n_in,
                              void* d_out, int out_size, void* d_ws, size_t ws_size,
                              hipStream_t stream) {
    const float* x        = (const float*)d_in[0];  // (8, 2048, 512) fp32
    const float* rotation = (const float*)d_in[1];  // (512, 8) fp32
    float* out = (float*)d_out;                     // (8, 2048, 2048) fp32

    float* rotT = (float*)d_ws;                     // 8 x 8 x 2048 = 512 KiB

    qa_rot<<<NB * 64, 256, 0, stream>>>(x, rotation, rotT);
    qa_scores<<<NB * 256, K2_THREADS, 0, stream>>>(rotT, out);
}